// Round 2
// baseline (465.397 us; speedup 1.0000x reference)
//
#include <hip/hip_runtime.h>
#include <math.h>

// Problem constants (from reference)
#define B_   8
#define S_   2048
#define DIN_ 4096
#define DOUT_ 4096
#define THRESH_ 0.1f
#define LN_EPS_ 1e-5f

#define NROWS (B_ * S_)

// ---------------------------------------------------------------------------
// Kernel 1: scan weight [DOUT, DIN] for ternary nonzeros (|w| >= THRESH).
// Encode each as (flat_index << 1) | (sign<0), append to list via atomic.
// With this input distribution, nnz ~ Poisson(2): weight=(u-0.5)*0.2 lies in
// [-0.1, 0.1) and only exact u==0 gives |w| >= 0.1f. Code is general
// regardless of nnz (up to ws capacity).
// ---------------------------------------------------------------------------
__global__ __launch_bounds__(256) void lbe_scan_kernel(
    const float* __restrict__ w, int* __restrict__ cnt,
    int* __restrict__ list, int cap) {
  int idx = blockIdx.x * blockDim.x + threadIdx.x;  // float4 index
  const int total4 = (DOUT_ * DIN_) / 4;
  if (idx >= total4) return;
  float4 v = reinterpret_cast<const float4*>(w)[idx];
  const float* vp = &v.x;
#pragma unroll
  for (int j = 0; j < 4; ++j) {
    float wv = vp[j];
    if (fabsf(wv) >= THRESH_) {
      int flat = idx * 4 + j;                       // o*DIN + i, < 2^24
      int e = (flat << 1) | (wv < 0.f ? 1 : 0);
      int pos = atomicAdd(cnt, 1);
      if (pos < cap) list[pos] = e;
    }
  }
}

// ---------------------------------------------------------------------------
// Kernel 2: one block (256 threads) per (b,s) row.
//  - dense LDS dot[DOUT] zero-init, sparse-accumulate list entries
//  - y[o] = (dot[o] + bias[o]) * scale[o]
//  - block-reduce mean/var, LayerNorm, tanh(y/qs), round to 1/127 grid
// Output writes are the dominant traffic (256 consecutive floats per
// iteration per block -> fully coalesced).
// ---------------------------------------------------------------------------
__global__ __launch_bounds__(256) void lbe_row_kernel(
    const float* __restrict__ x, const float* __restrict__ bias,
    const float* __restrict__ scale, const float* __restrict__ gamma,
    const float* __restrict__ beta, const float* __restrict__ qs,
    const int* __restrict__ cnt, const int* __restrict__ list, int cap,
    float* __restrict__ out) {
  __shared__ float sdot[DOUT_];
  __shared__ float sred[16];
  __shared__ float sstats[2];

  const int tid = threadIdx.x;
  const int row = blockIdx.x;
  const float* __restrict__ xr = x + (size_t)row * DIN_;

  // zero the dense dot array
#pragma unroll
  for (int k = 0; k < DOUT_ / 256; ++k) sdot[tid + k * 256] = 0.f;
  __syncthreads();

  // sparse accumulation (nnz is tiny; all blocks read the same cached list)
  int n = *cnt;
  if (n > cap) n = cap;
  for (int e = tid; e < n; e += 256) {
    int ev = list[e];
    int flat = ev >> 1;
    int o = flat >> 12;            // DIN = 4096 = 2^12
    int i = flat & (DIN_ - 1);
    float c = xr[i];
    if (ev & 1) c = -c;
    atomicAdd(&sdot[o], c);
  }
  __syncthreads();

  // y = (dot + bias) * scale; accumulate sum and sum-of-squares
  float s1 = 0.f, s2 = 0.f;
  float yv[DOUT_ / 256];
#pragma unroll
  for (int k = 0; k < DOUT_ / 256; ++k) {
    int o = tid + k * 256;
    float y = (sdot[o] + bias[o]) * scale[o];
    yv[k] = y;
    s1 += y;
    s2 += y * y;
  }

  // wave (64-lane) butterfly reduce, then cross-wave via LDS
#pragma unroll
  for (int off = 32; off > 0; off >>= 1) {
    s1 += __shfl_down(s1, off);
    s2 += __shfl_down(s2, off);
  }
  int wid = tid >> 6, lane = tid & 63;
  if (lane == 0) { sred[wid] = s1; sred[8 + wid] = s2; }
  __syncthreads();
  if (tid == 0) {
    float a = 0.f, b = 0.f;
#pragma unroll
    for (int wv = 0; wv < 4; ++wv) { a += sred[wv]; b += sred[8 + wv]; }
    float mu = a * (1.f / DOUT_);
    float var = b * (1.f / DOUT_) - mu * mu;
    if (var < 0.f) var = 0.f;
    sstats[0] = mu;
    sstats[1] = rsqrtf(var + LN_EPS_);
  }
  __syncthreads();
  const float mu = sstats[0];
  const float rs = sstats[1];
  const float iq = 1.f / qs[0];

  float* __restrict__ orow = out + (size_t)row * DOUT_;
#pragma unroll
  for (int k = 0; k < DOUT_ / 256; ++k) {
    int o = tid + k * 256;
    float yn = (yv[k] - mu) * rs * gamma[o] + beta[o];
    float t = tanhf(yn * iq);
    orow[o] = rintf(t * 127.f) * (1.f / 127.f);
  }
}

extern "C" void kernel_launch(void* const* d_in, const int* in_sizes, int n_in,
                              void* d_out, int out_size, void* d_ws, size_t ws_size,
                              hipStream_t stream) {
  const float* x     = (const float*)d_in[0];  // [B,S,DIN]
  const float* w     = (const float*)d_in[1];  // [DOUT,DIN]
  const float* bias  = (const float*)d_in[2];  // [DOUT]
  const float* scale = (const float*)d_in[3];  // [DOUT]
  const float* gamma = (const float*)d_in[4];  // [DOUT]
  const float* beta  = (const float*)d_in[5];  // [DOUT]
  const float* qs    = (const float*)d_in[6];  // [1]
  float* out = (float*)d_out;

  int* cnt = (int*)d_ws;
  int* list = (int*)((char*)d_ws + 256);
  long long avail = (long long)ws_size - 256;
  int cap = avail > 0 ? (int)(avail / 4) : 0;
  if (cap > (1 << 24)) cap = 1 << 24;

  // zero the nnz counter (d_ws is re-poisoned to 0xAA before every launch)
  hipMemsetAsync(d_ws, 0, 4, stream);

  {
    const int total4 = (DOUT_ * DIN_) / 4;
    int blocks = (total4 + 255) / 256;
    lbe_scan_kernel<<<blocks, 256, 0, stream>>>(w, cnt, list, cap);
  }
  lbe_row_kernel<<<NROWS, 256, 0, stream>>>(x, bias, scale, gamma, beta, qs,
                                            cnt, list, cap, out);
}

// Round 6
// 456.722 us; speedup vs baseline: 1.0190x; 1.0190x over previous
//
#include <hip/hip_runtime.h>
#include <math.h>

// Problem constants (from reference)
#define B_   8
#define S_   2048
#define DIN_ 4096
#define DOUT_ 4096
#define THRESH_ 0.1f
#define LN_EPS_ 1e-5f

#define NROWS (B_ * S_)

// ---------------------------------------------------------------------------
// Fast exact-enough tanh-quantize: out = rint(127*tanh(z*iq))/127.
// tanh via v_exp_f32 + v_rcp_f32. Max error ~1e-6 in tanh; only matters at a
// quantization bin boundary -> at most 1/127 = 0.0079 output delta, far
// below the 2e-2 absmax threshold.
// ---------------------------------------------------------------------------
__device__ __forceinline__ float qtanh(float z, float iq) {
  float t = z * iq;
  t = fminf(fmaxf(t, -9.f), 9.f);          // tanh(+-9) == +-1 in fp32
  float e2 = __expf(2.f * t);              // v_exp_f32 (2^x) w/ log2e fold
  float r = (e2 - 1.f) * __builtin_amdgcn_rcpf(e2 + 1.f);
  return rintf(r * 127.f) * (1.f / 127.f);
}

// ---------------------------------------------------------------------------
// Kernel 1: scan weight [DOUT, DIN] for ternary nonzeros (|w| >= THRESH).
// Encode each as (flat_index << 1) | (sign<0), append to list via atomic.
// With this input distribution, nnz ~ Poisson(2): weight=(u-0.5)*0.2 lies in
// [-0.1, 0.1) and only exact u==0 gives |w| >= 0.1f. Code is general
// regardless of nnz (up to ws capacity).
// ---------------------------------------------------------------------------
__global__ __launch_bounds__(256) void lbe_scan_kernel(
    const float* __restrict__ w, int* __restrict__ cnt,
    int* __restrict__ list, int cap) {
  int idx = blockIdx.x * blockDim.x + threadIdx.x;  // float4 index
  const int total4 = (DOUT_ * DIN_) / 4;
  if (idx >= total4) return;
  float4 v = reinterpret_cast<const float4*>(w)[idx];
  const float* vp = &v.x;
#pragma unroll
  for (int j = 0; j < 4; ++j) {
    float wv = vp[j];
    if (fabsf(wv) >= THRESH_) {
      int flat = idx * 4 + j;                       // o*DIN + i, < 2^24
      int e = (flat << 1) | (wv < 0.f ? 1 : 0);
      int pos = atomicAdd(cnt, 1);
      if (pos < cap) list[pos] = e;
    }
  }
}

// ---------------------------------------------------------------------------
// Kernel 2: one block (256 threads) per (b,s) row. Fully float4-vectorized.
//  - dense LDS dot[DOUT] zero-init, sparse-accumulate list entries
//  - y[o] = (dot[o] + bias[o]) * scale[o]
//  - block-reduce mean/var, LayerNorm, fast tanh(y/qs), round to 1/127 grid
// ---------------------------------------------------------------------------
__global__ __launch_bounds__(256) void lbe_row_kernel(
    const float* __restrict__ x, const float* __restrict__ bias,
    const float* __restrict__ scale, const float* __restrict__ gamma,
    const float* __restrict__ beta, const float* __restrict__ qs,
    const int* __restrict__ cnt, const int* __restrict__ list, int cap,
    float* __restrict__ out) {
  __shared__ float sdot[DOUT_];
  __shared__ float sred[16];
  __shared__ float sstats[2];

  const int tid = threadIdx.x;
  const int row = blockIdx.x;
  const float* __restrict__ xr = x + (size_t)row * DIN_;

  // zero the dense dot array (float4)
  const float4 z4 = {0.f, 0.f, 0.f, 0.f};
#pragma unroll
  for (int k = 0; k < 4; ++k)
    reinterpret_cast<float4*>(sdot)[tid + k * 256] = z4;
  __syncthreads();

  // sparse accumulation (nnz is tiny; list is L2-resident for all blocks)
  int n = *cnt;
  if (n > cap) n = cap;
  for (int e = tid; e < n; e += 256) {
    int ev = list[e];
    int flat = ev >> 1;
    int o = flat >> 12;            // DIN = 4096 = 2^12
    int i = flat & (DIN_ - 1);
    float c = xr[i];
    if (ev & 1) c = -c;
    atomicAdd(&sdot[o], c);
  }
  __syncthreads();

  // y = (dot + bias) * scale; accumulate sum and sum-of-squares (float4)
  float s1 = 0.f, s2 = 0.f;
  float4 yv[4];
#pragma unroll
  for (int k = 0; k < 4; ++k) {
    int o4 = tid + k * 256;        // float4 index
    float4 d  = reinterpret_cast<const float4*>(sdot)[o4];
    float4 bb = reinterpret_cast<const float4*>(bias)[o4];
    float4 ss = reinterpret_cast<const float4*>(scale)[o4];
    float4 y;
    y.x = (d.x + bb.x) * ss.x;
    y.y = (d.y + bb.y) * ss.y;
    y.z = (d.z + bb.z) * ss.z;
    y.w = (d.w + bb.w) * ss.w;
    yv[k] = y;
    s1 += (y.x + y.y) + (y.z + y.w);
    s2 = fmaf(y.x, y.x, s2);
    s2 = fmaf(y.y, y.y, s2);
    s2 = fmaf(y.z, y.z, s2);
    s2 = fmaf(y.w, y.w, s2);
  }

  // wave (64-lane) butterfly reduce, then cross-wave via LDS
#pragma unroll
  for (int off = 32; off > 0; off >>= 1) {
    s1 += __shfl_xor(s1, off);
    s2 += __shfl_xor(s2, off);
  }
  int wid = tid >> 6, lane = tid & 63;
  if (lane == 0) { sred[wid] = s1; sred[8 + wid] = s2; }
  __syncthreads();
  if (tid == 0) {
    float a = 0.f, b = 0.f;
#pragma unroll
    for (int wv = 0; wv < 4; ++wv) { a += sred[wv]; b += sred[8 + wv]; }
    float mu = a * (1.f / DOUT_);
    float var = b * (1.f / DOUT_) - mu * mu;
    if (var < 0.f) var = 0.f;
    sstats[0] = mu;
    sstats[1] = rsqrtf(var + LN_EPS_);
  }
  __syncthreads();
  const float mu = sstats[0];
  const float rs = sstats[1];
  const float iq = __builtin_amdgcn_rcpf(qs[0]);   // qs=10.0 -> exact enough
  // note: rcp(10) vs 1/10 differs by ~1ulp; feeds tanh arg -> negligible

  float* __restrict__ orow = out + (size_t)row * DOUT_;
#pragma unroll
  for (int k = 0; k < 4; ++k) {
    int o4 = tid + k * 256;
    float4 g4 = reinterpret_cast<const float4*>(gamma)[o4];
    float4 b4 = reinterpret_cast<const float4*>(beta)[o4];
    float4 y = yv[k], r;
    r.x = qtanh(fmaf((y.x - mu) * rs, g4.x, b4.x), iq);
    r.y = qtanh(fmaf((y.y - mu) * rs, g4.y, b4.y), iq);
    r.z = qtanh(fmaf((y.z - mu) * rs, g4.z, b4.z), iq);
    r.w = qtanh(fmaf((y.w - mu) * rs, g4.w, b4.w), iq);
    reinterpret_cast<float4*>(orow)[o4] = r;
  }
}

extern "C" void kernel_launch(void* const* d_in, const int* in_sizes, int n_in,
                              void* d_out, int out_size, void* d_ws, size_t ws_size,
                              hipStream_t stream) {
  const float* x     = (const float*)d_in[0];  // [B,S,DIN]
  const float* w     = (const float*)d_in[1];  // [DOUT,DIN]
  const float* bias  = (const float*)d_in[2];  // [DOUT]
  const float* scale = (const float*)d_in[3];  // [DOUT]
  const float* gamma = (const float*)d_in[4];  // [DOUT]
  const float* beta  = (const float*)d_in[5];  // [DOUT]
  const float* qs    = (const float*)d_in[6];  // [1]
  float* out = (float*)d_out;

  int* cnt = (int*)d_ws;
  int* list = (int*)((char*)d_ws + 256);
  long long avail = (long long)ws_size - 256;
  int cap = avail > 0 ? (int)(avail / 4) : 0;
  if (cap > (1 << 24)) cap = 1 << 24;

  // zero the nnz counter (d_ws is re-poisoned to 0xAA before every launch)
  hipMemsetAsync(d_ws, 0, 4, stream);

  {
    const int total4 = (DOUT_ * DIN_) / 4;
    int blocks = (total4 + 255) / 256;
    lbe_scan_kernel<<<blocks, 256, 0, stream>>>(w, cnt, list, cap);
  }
  lbe_row_kernel<<<NROWS, 256, 0, stream>>>(x, bias, scale, gamma, beta, qs,
                                            cnt, list, cap, out);
}

// Round 9
// 442.645 us; speedup vs baseline: 1.0514x; 1.0318x over previous
//
#include <hip/hip_runtime.h>
#include <math.h>

// Problem constants (from reference)
#define B_   8
#define S_   2048
#define DIN_ 4096
#define DOUT_ 4096
#define THRESH_ 0.1f
#define LN_EPS_ 1e-5f

#define NROWS (B_ * S_)
#define RPB 8                      // rows per block in the row kernel

// ---------------------------------------------------------------------------
// Fast tanh-quantize: out = rint(127*tanh(z*iq))/127 via v_exp_f32+v_rcp_f32.
// Max tanh error ~1e-6 -> only matters at a bin boundary -> <= 1/127 output
// delta, far below the 2e-2 threshold. (Round 6 measured absmax 0.0.)
// ---------------------------------------------------------------------------
__device__ __forceinline__ float qtanh(float z, float iq) {
  float t = z * iq;
  t = fminf(fmaxf(t, -9.f), 9.f);
  float e2 = __expf(2.f * t);
  float r = (e2 - 1.f) * __builtin_amdgcn_rcpf(e2 + 1.f);
  return rintf(r * 127.f) * (1.f / 127.f);
}

// ---------------------------------------------------------------------------
// Kernel 1: scan weight [DOUT, DIN] for ternary nonzeros (|w| >= THRESH).
// nnz ~ Poisson(2) for this init (weight=(u-0.5)*0.2 in [-0.1,0.1); only
// exact u==0 survives). General for any nnz up to ws capacity.
// ---------------------------------------------------------------------------
__global__ __launch_bounds__(256) void lbe_scan_kernel(
    const float* __restrict__ w, int* __restrict__ cnt,
    int* __restrict__ list, int cap) {
  int idx = blockIdx.x * blockDim.x + threadIdx.x;  // float4 index
  const int total4 = (DOUT_ * DIN_) / 4;
  if (idx >= total4) return;
  float4 v = reinterpret_cast<const float4*>(w)[idx];
  const float* vp = &v.x;
#pragma unroll
  for (int j = 0; j < 4; ++j) {
    float wv = vp[j];
    if (fabsf(wv) >= THRESH_) {
      int flat = idx * 4 + j;                       // o*DIN + i, < 2^24
      int e = (flat << 1) | (wv < 0.f ? 1 : 0);
      int pos = atomicAdd(cnt, 1);
      if (pos < cap) list[pos] = e;
    }
  }
}

// ---------------------------------------------------------------------------
// Kernel 2 (1 block): S0 = sum(bias*scale), Q0 = sum((bias*scale)^2).
// These are the input-independent parts of the LN mean / second moment:
// y_o = (dot_o + b_o)*s_o and dot_o == 0 for all non-hit channels.
// ---------------------------------------------------------------------------
__global__ __launch_bounds__(256) void lbe_base_kernel(
    const float* __restrict__ bias, const float* __restrict__ scale,
    float* __restrict__ sq) {
  int tid = threadIdx.x;
  float s = 0.f, q = 0.f;
#pragma unroll
  for (int k = 0; k < 4; ++k) {
    float4 b  = reinterpret_cast<const float4*>(bias)[tid + k * 256];
    float4 sc = reinterpret_cast<const float4*>(scale)[tid + k * 256];
    float p;
    p = b.x * sc.x; s += p; q = fmaf(p, p, q);
    p = b.y * sc.y; s += p; q = fmaf(p, p, q);
    p = b.z * sc.z; s += p; q = fmaf(p, p, q);
    p = b.w * sc.w; s += p; q = fmaf(p, p, q);
  }
#pragma unroll
  for (int off = 32; off > 0; off >>= 1) {
    s += __shfl_xor(s, off);
    q += __shfl_xor(q, off);
  }
  __shared__ float red[8];
  int wid = tid >> 6, lane = tid & 63;
  if (lane == 0) { red[wid] = s; red[4 + wid] = q; }
  __syncthreads();
  if (tid == 0) {
    sq[0] = red[0] + red[1] + red[2] + red[3];
    sq[1] = red[4] + red[5] + red[6] + red[7];
  }
}

// ---------------------------------------------------------------------------
// Kernel 3: one thread per row -> mu[row], rs[row].
// Corrections from the nnz hit channels only (dedupe repeated o via O(n^2)
// scan; n is tiny). var formula identical algebraically to the reference's
// mean((y-mu)^2); fp32 ordering deltas ~1e-7 relative.
// ---------------------------------------------------------------------------
__global__ __launch_bounds__(256) void lbe_stats_kernel(
    const float* __restrict__ x, const float* __restrict__ bias,
    const float* __restrict__ scale, const int* __restrict__ cnt,
    const int* __restrict__ list, int cap, const float* __restrict__ sq,
    float* __restrict__ murs) {
  int row = blockIdx.x * blockDim.x + threadIdx.x;
  if (row >= NROWS) return;
  int n = *cnt; if (n > cap) n = cap;
  const float* __restrict__ xr = x + (size_t)row * DIN_;
  float dS = 0.f, dQ = 0.f;
  for (int e = 0; e < n; ++e) {
    int ev = list[e];
    int o = ev >> 13;                      // (ev>>1)>>12
    bool first = true;
    for (int e2 = 0; e2 < e; ++e2)
      if ((list[e2] >> 13) == o) { first = false; break; }
    if (!first) continue;
    int i = (ev >> 1) & (DIN_ - 1);
    float dotO = (ev & 1) ? -xr[i] : xr[i];
    for (int e2 = e + 1; e2 < n; ++e2) {
      int ev2 = list[e2];
      if ((ev2 >> 13) == o) {
        float c2 = xr[(ev2 >> 1) & (DIN_ - 1)];
        dotO += (ev2 & 1) ? -c2 : c2;
      }
    }
    float bo = bias[o], so = scale[o];
    float t1 = (dotO + bo) * so;
    float t0 = bo * so;
    dS += dotO * so;
    dQ += t1 * t1 - t0 * t0;
  }
  float S = sq[0] + dS, Q = sq[1] + dQ;
  float mu = S * (1.f / DOUT_);
  float var = Q * (1.f / DOUT_) - mu * mu;
  if (var < 0.f) var = 0.f;
  murs[row] = mu;
  murs[NROWS + row] = rsqrtf(var + LN_EPS_);
}

// ---------------------------------------------------------------------------
// Kernel 4: streaming epilogue. 256 threads x RPB rows per block; each thread
// owns 16 channels (4 float4 groups, layout o4 = tid + k*256). No LDS, no
// syncs, no reductions. Params preloaded into registers once per block.
// Sparse dots accumulate via compile-time-indexed predicated adds.
// ---------------------------------------------------------------------------
__global__ __launch_bounds__(256) void lbe_row_kernel(
    const float* __restrict__ x, const float* __restrict__ bias,
    const float* __restrict__ scale, const float* __restrict__ gamma,
    const float* __restrict__ beta, const float* __restrict__ qs,
    const int* __restrict__ cnt, const int* __restrict__ list, int cap,
    const float* __restrict__ murs, float* __restrict__ out) {
  const int tid = threadIdx.x;
  float4 b4[4], s4[4], g4[4], e4[4];
#pragma unroll
  for (int k = 0; k < 4; ++k) {
    int o4 = tid + k * 256;
    b4[k] = reinterpret_cast<const float4*>(bias)[o4];
    s4[k] = reinterpret_cast<const float4*>(scale)[o4];
    g4[k] = reinterpret_cast<const float4*>(gamma)[o4];
    e4[k] = reinterpret_cast<const float4*>(beta)[o4];
  }
  int n = *cnt; if (n > cap) n = cap;
  const float iq = __builtin_amdgcn_rcpf(qs[0]);   // qs=10 -> ~1ulp, feeds tanh arg

  const int row0 = blockIdx.x * RPB;
  for (int r = 0; r < RPB; ++r) {
    const int row = row0 + r;
    const float* __restrict__ xr = x + (size_t)row * DIN_;
    float4 d[4];
#pragma unroll
    for (int k = 0; k < 4; ++k) d[k] = make_float4(0.f, 0.f, 0.f, 0.f);
    for (int e = 0; e < n; ++e) {
      int ev = list[e];
      int o = ev >> 13;
      float c = xr[(ev >> 1) & (DIN_ - 1)];        // broadcast load
      if (ev & 1) c = -c;
#pragma unroll
      for (int k = 0; k < 4; ++k) {
        int base = (tid + k * 256) << 2;
        d[k].x += (o == base + 0) ? c : 0.f;
        d[k].y += (o == base + 1) ? c : 0.f;
        d[k].z += (o == base + 2) ? c : 0.f;
        d[k].w += (o == base + 3) ? c : 0.f;
      }
    }
    const float mu = murs[row];
    const float rs = murs[NROWS + row];
    float* __restrict__ orow = out + (size_t)row * DOUT_;
#pragma unroll
    for (int k = 0; k < 4; ++k) {
      float4 y, rr;
      y.x = (d[k].x + b4[k].x) * s4[k].x;
      y.y = (d[k].y + b4[k].y) * s4[k].y;
      y.z = (d[k].z + b4[k].z) * s4[k].z;
      y.w = (d[k].w + b4[k].w) * s4[k].w;
      rr.x = qtanh(fmaf((y.x - mu) * rs, g4[k].x, e4[k].x), iq);
      rr.y = qtanh(fmaf((y.y - mu) * rs, g4[k].y, e4[k].y), iq);
      rr.z = qtanh(fmaf((y.z - mu) * rs, g4[k].z, e4[k].z), iq);
      rr.w = qtanh(fmaf((y.w - mu) * rs, g4[k].w, e4[k].w), iq);
      reinterpret_cast<float4*>(orow)[tid + k * 256] = rr;
    }
  }
}

extern "C" void kernel_launch(void* const* d_in, const int* in_sizes, int n_in,
                              void* d_out, int out_size, void* d_ws, size_t ws_size,
                              hipStream_t stream) {
  const float* x     = (const float*)d_in[0];  // [B,S,DIN]
  const float* w     = (const float*)d_in[1];  // [DOUT,DIN]
  const float* bias  = (const float*)d_in[2];  // [DOUT]
  const float* scale = (const float*)d_in[3];  // [DOUT]
  const float* gamma = (const float*)d_in[4];  // [DOUT]
  const float* beta  = (const float*)d_in[5];  // [DOUT]
  const float* qs    = (const float*)d_in[6];  // [1]
  float* out = (float*)d_out;

  // ws layout: [0..4) cnt | [16..24) S0,Q0 | [256 ..) mu/rs (2*NROWS floats)
  //            | list afterwards
  int*   cnt  = (int*)d_ws;
  float* sq   = (float*)((char*)d_ws + 16);
  float* murs = (float*)((char*)d_ws + 256);
  const size_t list_off = 256 + (size_t)2 * NROWS * 4;
  int* list = (int*)((char*)d_ws + list_off);
  long long avail = (long long)ws_size - (long long)list_off;
  int cap = avail > 0 ? (int)(avail / 4) : 0;
  if (cap > (1 << 24)) cap = 1 << 24;

  hipMemsetAsync(d_ws, 0, 4, stream);   // zero nnz counter

  {
    const int total4 = (DOUT_ * DIN_) / 4;
    lbe_scan_kernel<<<(total4 + 255) / 256, 256, 0, stream>>>(w, cnt, list, cap);
  }
  lbe_base_kernel<<<1, 256, 0, stream>>>(bias, scale, sq);
  lbe_stats_kernel<<<NROWS / 256, 256, 0, stream>>>(x, bias, scale, cnt, list,
                                                    cap, sq, murs);
  lbe_row_kernel<<<NROWS / RPB, 256, 0, stream>>>(x, bias, scale, gamma, beta,
                                                  qs, cnt, list, cap, murs, out);
}